// Round 1
// baseline (1631.124 us; speedup 1.0000x reference)
//
#include <hip/hip_runtime.h>
#include <hip/hip_bf16.h>

#define N_NODES 50000
#define E_EDGES 800000
#define ETOT (E_EDGES + N_NODES)
#define HC 256
#define NHEAD 4
#define CHAN 64
#define NEG 0.2f
#define CAP 512   // max edges cached in LDS per dst node (Poisson(17) => max ~50; fallback handles more)

// ---------------- CSR build (once per call; shared across all 5 layers) ----------------

__global__ void count_kernel(const int* __restrict__ ei, int* __restrict__ counts) {
    int i = blockIdx.x * blockDim.x + threadIdx.x;
    if (i >= ETOT) return;
    int dst = (i < E_EDGES) ? ei[E_EDGES + i] : (i - E_EDGES);
    atomicAdd(&counts[dst], 1);
}

__global__ void scan_kernel(const int* __restrict__ counts, int* __restrict__ offsets,
                            int* __restrict__ cursor) {
    __shared__ int s[1024];
    int tid = threadIdx.x;
    int carry = 0;
    for (int base = 0; base < N_NODES; base += 1024) {
        int i = base + tid;
        int v = (i < N_NODES) ? counts[i] : 0;
        s[tid] = v;
        __syncthreads();
        for (int off = 1; off < 1024; off <<= 1) {
            int t = (tid >= off) ? s[tid - off] : 0;
            __syncthreads();
            s[tid] += t;
            __syncthreads();
        }
        int incl = s[tid];
        int total = s[1023];
        int excl = incl - v;
        if (i < N_NODES) { offsets[i] = carry + excl; cursor[i] = carry + excl; }
        carry += total;
        __syncthreads();
    }
    if (tid == 0) offsets[N_NODES] = carry;
}

__global__ void fill_kernel(const int* __restrict__ ei, int* __restrict__ cursor,
                            int* __restrict__ csr_src) {
    int i = blockIdx.x * blockDim.x + threadIdx.x;
    if (i >= ETOT) return;
    int src, dst;
    if (i < E_EDGES) { src = ei[i]; dst = ei[E_EDGES + i]; }
    else             { src = i - E_EDGES; dst = src; }
    int pos = atomicAdd(&cursor[dst], 1);
    csr_src[pos] = src;
}

// ---------------- fp32 GEMM: H[M,256] = (A1 (+A2)) @ W[K,256] ----------------
// 64x64 tile, BK=16, 256 threads, 4x4 microtile.

__global__ __launch_bounds__(256) void gemm_kernel(const float* __restrict__ A1,
                                                   const float* __restrict__ A2,
                                                   const float* __restrict__ W,
                                                   float* __restrict__ H, int M, int K) {
    __shared__ float As[16][68];   // [k][m], padded
    __shared__ float Bs[16][68];   // [k][n], padded
    int tid = threadIdx.x;
    int m0 = blockIdx.x * 64, n0 = blockIdx.y * 64;
    int ty = tid >> 4, tx = tid & 15;
    float acc[4][4] = {};
    int ar = tid >> 2;            // 0..63  (A tile row)
    int ac = (tid & 3) * 4;       // 0,4,8,12 (A tile col base)
    int br = tid >> 4;            // 0..15  (B tile row)
    int bc = (tid & 15) * 4;      // 0..60  (B tile col base)

    for (int k0 = 0; k0 < K; k0 += 16) {
        float4 av = make_float4(0.f, 0.f, 0.f, 0.f);
        int row = m0 + ar;
        if (row < M) {
            av = *(const float4*)(A1 + (size_t)row * K + k0 + ac);
            if (A2) {
                float4 bv = *(const float4*)(A2 + (size_t)row * K + k0 + ac);
                av.x += bv.x; av.y += bv.y; av.z += bv.z; av.w += bv.w;
            }
        }
        As[ac + 0][ar] = av.x; As[ac + 1][ar] = av.y;
        As[ac + 2][ar] = av.z; As[ac + 3][ar] = av.w;
        float4 wv = *(const float4*)(W + (size_t)(k0 + br) * HC + n0 + bc);
        *(float4*)&Bs[br][bc] = wv;
        __syncthreads();
        #pragma unroll
        for (int c = 0; c < 16; ++c) {
            float4 a4 = *(const float4*)&As[c][ty * 4];
            float4 b4 = *(const float4*)&Bs[c][tx * 4];
            float aa[4] = {a4.x, a4.y, a4.z, a4.w};
            float bb[4] = {b4.x, b4.y, b4.z, b4.w};
            #pragma unroll
            for (int i = 0; i < 4; ++i)
                #pragma unroll
                for (int j = 0; j < 4; ++j)
                    acc[i][j] += aa[i] * bb[j];
        }
        __syncthreads();
    }
    #pragma unroll
    for (int i = 0; i < 4; ++i) {
        int row = m0 + ty * 4 + i;
        if (row < M) {
            float4 o = make_float4(acc[i][0], acc[i][1], acc[i][2], acc[i][3]);
            *(float4*)(H + (size_t)row * HC + n0 + tx * 4) = o;
        }
    }
}

// ---------------- per-node attention logits: es[n,h]=<h[n,h,:],a_src[h]>, ed likewise ----------------
// one wave per node (lane -> 4 channels), 4 nodes per block

__global__ __launch_bounds__(256) void esed_kernel(const float* __restrict__ H,
                                                   const float* __restrict__ a_src,
                                                   const float* __restrict__ a_dst,
                                                   float* __restrict__ es, float* __restrict__ ed) {
    int tid = threadIdx.x;
    int lane = tid & 63;
    int node = blockIdx.x * 4 + (tid >> 6);
    int head = lane >> 4;
    int cc = (lane & 15) * 4;
    float4 h4 = *(const float4*)(H + (size_t)node * HC + lane * 4);
    float4 as = *(const float4*)(a_src + head * CHAN + cc);
    float4 ad = *(const float4*)(a_dst + head * CHAN + cc);
    float ps = h4.x * as.x + h4.y * as.y + h4.z * as.z + h4.w * as.w;
    float pd = h4.x * ad.x + h4.y * ad.y + h4.z * ad.z + h4.w * ad.w;
    #pragma unroll
    for (int m = 1; m < 16; m <<= 1) {
        ps += __shfl_xor(ps, m, 64);
        pd += __shfl_xor(pd, m, 64);
    }
    if ((lane & 15) == 0) {
        es[node * NHEAD + head] = ps;
        ed[node * NHEAD + head] = pd;
    }
}

// ---------------- fused edge-softmax + aggregation: one block (4 waves) per dst node ----------------

__global__ __launch_bounds__(256) void gat_aggregate_kernel(
        const float* __restrict__ H, const float* __restrict__ es, const float* __restrict__ ed,
        const int* __restrict__ offsets, const int* __restrict__ csr_src,
        const float* __restrict__ bias, float* __restrict__ out, int do_relu) {
    __shared__ float e_lds[CAP * 4];
    __shared__ int   src_lds[CAP];
    __shared__ float red[4 * 64 * 4];
    __shared__ float stat[4 * 8];
    __shared__ float fin[8];
    int n = blockIdx.x;
    int tid = threadIdx.x;
    int w = tid >> 6, lane = tid & 63;
    int off = offsets[n];
    int deg = offsets[n + 1] - off;
    float4 edv = *(const float4*)(ed + n * 4);

    // Phase A: online softmax stats over all incoming edges; cache e + src in LDS
    float m[4] = {-1e30f, -1e30f, -1e30f, -1e30f};
    float l[4] = {0.f, 0.f, 0.f, 0.f};
    for (int jj = tid; jj < deg; jj += 256) {
        int s = csr_src[off + jj];
        float4 esv = *(const float4*)(es + (size_t)s * 4);
        float e[4] = {esv.x + edv.x, esv.y + edv.y, esv.z + edv.z, esv.w + edv.w};
        #pragma unroll
        for (int h = 0; h < 4; ++h) {
            e[h] = (e[h] > 0.f) ? e[h] : NEG * e[h];
            float M2 = fmaxf(m[h], e[h]);
            l[h] = l[h] * __expf(m[h] - M2) + __expf(e[h] - M2);
            m[h] = M2;
        }
        if (jj < CAP) {
            src_lds[jj] = s;
            #pragma unroll
            for (int h = 0; h < 4; ++h) e_lds[jj * 4 + h] = e[h];
        }
    }
    // wave reduce (m,l)
    #pragma unroll
    for (int msk = 1; msk < 64; msk <<= 1) {
        #pragma unroll
        for (int h = 0; h < 4; ++h) {
            float mo = __shfl_xor(m[h], msk, 64);
            float lo = __shfl_xor(l[h], msk, 64);
            float M2 = fmaxf(m[h], mo);
            l[h] = l[h] * __expf(m[h] - M2) + lo * __expf(mo - M2);
            m[h] = M2;
        }
    }
    if (lane == 0) {
        #pragma unroll
        for (int h = 0; h < 4; ++h) { stat[w * 8 + h] = m[h]; stat[w * 8 + 4 + h] = l[h]; }
    }
    __syncthreads();
    if (tid < 4) {
        int h = tid;
        float M2 = -1e30f, L = 0.f;
        for (int ww = 0; ww < 4; ++ww) {
            float mo = stat[ww * 8 + h], lo = stat[ww * 8 + 4 + h];
            float Mn = fmaxf(M2, mo);
            L = L * __expf(M2 - Mn) + lo * __expf(mo - Mn);
            M2 = Mn;
        }
        fin[h] = M2;
        fin[4 + h] = 1.f / (L + 1e-16f);
    }
    __syncthreads();
    float fm[4] = {fin[0], fin[1], fin[2], fin[3]};
    float fr[4] = {fin[4], fin[5], fin[6], fin[7]};
    int degc = deg < CAP ? deg : CAP;
    // convert cached e -> alpha
    for (int jj = tid; jj < degc; jj += 256) {
        #pragma unroll
        for (int h = 0; h < 4; ++h)
            e_lds[jj * 4 + h] = __expf(e_lds[jj * 4 + h] - fm[h]) * fr[h];
    }
    __syncthreads();

    // Phase B: each wave handles every 4th edge; lane covers 4 channels (all 256 per wave)
    int head = lane >> 4;
    float4 acc = make_float4(0.f, 0.f, 0.f, 0.f);
    for (int jj = w; jj < degc; jj += 4) {
        int s = src_lds[jj];
        float alpha = e_lds[jj * 4 + head];
        float4 h4 = *(const float4*)(H + (size_t)s * HC + lane * 4);
        acc.x += alpha * h4.x; acc.y += alpha * h4.y;
        acc.z += alpha * h4.z; acc.w += alpha * h4.w;
    }
    // fallback for pathological degree > CAP
    for (int jj = CAP + w; jj < deg; jj += 4) {
        int s = csr_src[off + jj];
        float e = es[(size_t)s * 4 + head] + ((const float*)&edv)[head];
        e = (e > 0.f) ? e : NEG * e;
        float alpha = __expf(e - fm[head]) * fr[head];
        float4 h4 = *(const float4*)(H + (size_t)s * HC + lane * 4);
        acc.x += alpha * h4.x; acc.y += alpha * h4.y;
        acc.z += alpha * h4.z; acc.w += alpha * h4.w;
    }
    *(float4*)&red[(w * 64 + lane) * 4] = acc;
    __syncthreads();
    if (w == 0) {
        float4 a0 = *(const float4*)&red[(0 * 64 + lane) * 4];
        float4 a1 = *(const float4*)&red[(1 * 64 + lane) * 4];
        float4 a2 = *(const float4*)&red[(2 * 64 + lane) * 4];
        float4 a3 = *(const float4*)&red[(3 * 64 + lane) * 4];
        float4 b4 = *(const float4*)(bias + lane * 4);
        float4 o;
        o.x = a0.x + a1.x + a2.x + a3.x + b4.x;
        o.y = a0.y + a1.y + a2.y + a3.y + b4.y;
        o.z = a0.z + a1.z + a2.z + a3.z + b4.z;
        o.w = a0.w + a1.w + a2.w + a3.w + b4.w;
        if (do_relu) {
            o.x = fmaxf(o.x, 0.f); o.y = fmaxf(o.y, 0.f);
            o.z = fmaxf(o.z, 0.f); o.w = fmaxf(o.w, 0.f);
        }
        *(float4*)(out + (size_t)n * HC + lane * 4) = o;
    }
}

// ---------------- launch ----------------

extern "C" void kernel_launch(void* const* d_in, const int* in_sizes, int n_in,
                              void* d_out, int out_size, void* d_ws, size_t ws_size,
                              hipStream_t stream) {
    const float* x  = (const float*)d_in[0];
    const int*   ei = (const int*)d_in[1];
    const float *W[5], *Asrc[5], *Adst[5], *Bs[5];
    for (int l = 0; l < 4; ++l) {
        W[l]    = (const float*)d_in[2 + l * 4];
        Asrc[l] = (const float*)d_in[3 + l * 4];
        Adst[l] = (const float*)d_in[4 + l * 4];
        Bs[l]   = (const float*)d_in[5 + l * 4];
    }
    W[4] = W[3]; Asrc[4] = Asrc[3]; Adst[4] = Adst[3]; Bs[4] = Bs[3];  // layer5 reuses conv4

    char* ws = (char*)d_ws;
    size_t off = 0;
    auto alloc = [&](size_t bytes) -> void* {
        void* p = ws + off;
        off += (bytes + 255) & ~(size_t)255;
        return p;
    };
    float* h       = (float*)alloc((size_t)N_NODES * HC * 4);
    float* xa      = (float*)alloc((size_t)N_NODES * HC * 4);
    float* xb      = (float*)alloc((size_t)N_NODES * HC * 4);
    float* xc      = (float*)alloc((size_t)N_NODES * HC * 4);
    float* es      = (float*)alloc((size_t)N_NODES * 4 * 4);
    float* ed      = (float*)alloc((size_t)N_NODES * 4 * 4);
    int*   counts  = (int*)alloc((size_t)N_NODES * 4);
    int*   offsets = (int*)alloc((size_t)(N_NODES + 1) * 4);
    int*   cursor  = (int*)alloc((size_t)N_NODES * 4);
    int*   csr_src = (int*)alloc((size_t)ETOT * 4);

    // CSR by dst, built once per call, reused across all 5 layers
    hipMemsetAsync(counts, 0, (size_t)N_NODES * 4, stream);
    count_kernel<<<(ETOT + 255) / 256, 256, 0, stream>>>(ei, counts);
    scan_kernel<<<1, 1024, 0, stream>>>(counts, offsets, cursor);
    fill_kernel<<<(ETOT + 255) / 256, 256, 0, stream>>>(ei, cursor, csr_src);

    auto layer = [&](const float* in1, const float* in2, int K, int l, float* outp, int relu) {
        dim3 g((N_NODES + 63) / 64, HC / 64);
        gemm_kernel<<<g, 256, 0, stream>>>(in1, in2, W[l], h, N_NODES, K);
        esed_kernel<<<N_NODES / 4, 256, 0, stream>>>(h, Asrc[l], Adst[l], es, ed);
        gat_aggregate_kernel<<<N_NODES, 256, 0, stream>>>(h, es, ed, offsets, csr_src,
                                                          Bs[l], outp, relu);
    };

    float* out = (float*)d_out;
    layer(x,  nullptr, 128, 0, xa, 1);  // x1 = relu(gat(x))
    layer(xa, nullptr, HC,  1, xb, 1);  // x2 = relu(gat(x1))
    layer(xb, xa,      HC,  2, xc, 1);  // x3 = relu(gat(x2+x1))
    layer(xb, xc,      HC,  3, xa, 1);  // x4 = relu(gat(x2+x3)), overwrites x1
    layer(xa, xc,      HC,  4, out, 0); // x5 = gat(x4+x3), no relu
}

// Round 2
// 1276.167 us; speedup vs baseline: 1.2781x; 1.2781x over previous
//
#include <hip/hip_runtime.h>
#include <hip/hip_bf16.h>

#define N_NODES 50000
#define E_EDGES 800000
#define ETOT (E_EDGES + N_NODES)
#define HC 256
#define NHEAD 4
#define CHAN 64
#define NEG 0.2f

typedef _Float16 half8 __attribute__((ext_vector_type(8)));
typedef _Float16 half4v __attribute__((ext_vector_type(4)));
typedef float float4v __attribute__((ext_vector_type(4)));

// ---------------- CSR build (once per call; shared across all 5 layers) ----------------

__global__ void count_kernel(const int* __restrict__ ei, int* __restrict__ counts) {
    int i = blockIdx.x * blockDim.x + threadIdx.x;
    if (i >= ETOT) return;
    int dst = (i < E_EDGES) ? ei[E_EDGES + i] : (i - E_EDGES);
    atomicAdd(&counts[dst], 1);
}

__global__ void scan_kernel(const int* __restrict__ counts, int* __restrict__ offsets,
                            int* __restrict__ cursor) {
    __shared__ int s[1024];
    int tid = threadIdx.x;
    int carry = 0;
    for (int base = 0; base < N_NODES; base += 1024) {
        int i = base + tid;
        int v = (i < N_NODES) ? counts[i] : 0;
        s[tid] = v;
        __syncthreads();
        for (int off = 1; off < 1024; off <<= 1) {
            int t = (tid >= off) ? s[tid - off] : 0;
            __syncthreads();
            s[tid] += t;
            __syncthreads();
        }
        int incl = s[tid];
        int total = s[1023];
        int excl = incl - v;
        if (i < N_NODES) { offsets[i] = carry + excl; cursor[i] = carry + excl; }
        carry += total;
        __syncthreads();
    }
    if (tid == 0) offsets[N_NODES] = carry;
}

__global__ void fill_kernel(const int* __restrict__ ei, int* __restrict__ cursor,
                            int* __restrict__ csr_src) {
    int i = blockIdx.x * blockDim.x + threadIdx.x;
    if (i >= ETOT) return;
    int src, dst;
    if (i < E_EDGES) { src = ei[i]; dst = ei[E_EDGES + i]; }
    else             { src = i - E_EDGES; dst = src; }
    int pos = atomicAdd(&cursor[dst], 1);
    csr_src[pos] = src;
}

// ---------------- weight pre-split: W[K][256] fp32 -> Wt_h/Wt_l [n][k] f16 ----------------

__global__ void wsplit_kernel(const float* __restrict__ W, _Float16* __restrict__ Wth,
                              _Float16* __restrict__ Wtl, int K) {
    int id = blockIdx.x * 256 + threadIdx.x;
    if (id >= K * 256) return;
    int n = id & 255, k = id >> 8;
    float w = W[(size_t)k * 256 + n];
    _Float16 h = (_Float16)w;
    _Float16 l = (_Float16)(w - (float)h);
    Wth[(size_t)n * K + k] = h;
    Wtl[(size_t)n * K + k] = l;
}

// ---------------- f16-split MFMA GEMM: H[M,256] = (A1 (+A2)) @ W[K,256] ----------------
// BM=128, BN=128, BK=32. 3-MFMA error-compensated chain => fp32-level accuracy.
// LDS pitch 40 f16 (80B): frag ds_read_b128 is ~conflict-free (2-way max).

#define LDK 40

__global__ __launch_bounds__(256) void gemm_mfma_kernel(
        const float* __restrict__ A1, const float* __restrict__ A2,
        const _Float16* __restrict__ Wth, const _Float16* __restrict__ Wtl,
        float* __restrict__ H, int M, int K) {
    __shared__ _Float16 Ah[128][LDK];
    __shared__ _Float16 Al[128][LDK];
    __shared__ _Float16 Bh[128][LDK];
    __shared__ _Float16 Bl[128][LDK];

    int tid = threadIdx.x;
    int m0 = blockIdx.x * 128;
    int n0 = blockIdx.y * 128;
    int w = tid >> 6, lane = tid & 63;
    int rm = (w & 1) * 64, rn = (w >> 1) * 64;
    int fr = lane & 15;
    int fk = (lane >> 4) * 8;

    // staging index precompute
    int ar = tid >> 3;            // 0..31 (A: 8 lanes/row of 32 floats)
    int ak = (tid & 7) * 4;       // 0..28
    int wr = tid >> 2;            // 0..63 (W: 4 lanes/row of 32 f16)
    int wk = (tid & 3) * 8;       // 0,8,16,24

    float4v acc[4][4];
    #pragma unroll
    for (int i = 0; i < 4; ++i)
        #pragma unroll
        for (int j = 0; j < 4; ++j)
            acc[i][j] = (float4v){0.f, 0.f, 0.f, 0.f};

    for (int k0 = 0; k0 < K; k0 += 32) {
        __syncthreads();
        // ---- stage A (+residual) as f16 hi/lo ----
        #pragma unroll
        for (int g = 0; g < 4; ++g) {
            int r = g * 32 + ar;
            int row = m0 + r;
            float4 v = make_float4(0.f, 0.f, 0.f, 0.f);
            if (row < M) {
                v = *(const float4*)(A1 + (size_t)row * K + k0 + ak);
                if (A2) {
                    float4 u = *(const float4*)(A2 + (size_t)row * K + k0 + ak);
                    v.x += u.x; v.y += u.y; v.z += u.z; v.w += u.w;
                }
            }
            half4v hv = {(_Float16)v.x, (_Float16)v.y, (_Float16)v.z, (_Float16)v.w};
            half4v lv = {(_Float16)(v.x - (float)hv[0]), (_Float16)(v.y - (float)hv[1]),
                         (_Float16)(v.z - (float)hv[2]), (_Float16)(v.w - (float)hv[3])};
            *(half4v*)&Ah[r][ak] = hv;
            *(half4v*)&Al[r][ak] = lv;
        }
        // ---- stage W (pre-split, [n][k] layout) ----
        #pragma unroll
        for (int g = 0; g < 2; ++g) {
            int r = g * 64 + wr;
            const _Float16* ph = Wth + (size_t)(n0 + r) * K + k0 + wk;
            const _Float16* pl = Wtl + (size_t)(n0 + r) * K + k0 + wk;
            *(half8*)&Bh[r][wk] = *(const half8*)ph;
            *(half8*)&Bl[r][wk] = *(const half8*)pl;
        }
        __syncthreads();
        // ---- fragments ----
        half8 afh[4], afl[4], bfh[4], bfl[4];
        #pragma unroll
        for (int t = 0; t < 4; ++t) {
            afh[t] = *(const half8*)&Ah[rm + t * 16 + fr][fk];
            afl[t] = *(const half8*)&Al[rm + t * 16 + fr][fk];
            bfh[t] = *(const half8*)&Bh[rn + t * 16 + fr][fk];
            bfl[t] = *(const half8*)&Bl[rn + t * 16 + fr][fk];
        }
        #pragma unroll
        for (int tm = 0; tm < 4; ++tm)
            #pragma unroll
            for (int tn = 0; tn < 4; ++tn) {
                float4v c = acc[tm][tn];
                c = __builtin_amdgcn_mfma_f32_16x16x32_f16(afl[tm], bfh[tn], c, 0, 0, 0);
                c = __builtin_amdgcn_mfma_f32_16x16x32_f16(afh[tm], bfl[tn], c, 0, 0, 0);
                c = __builtin_amdgcn_mfma_f32_16x16x32_f16(afh[tm], bfh[tn], c, 0, 0, 0);
                acc[tm][tn] = c;
            }
    }
    // ---- epilogue: C/D layout col=lane&15, row=(lane>>4)*4+i ----
    #pragma unroll
    for (int tm = 0; tm < 4; ++tm) {
        int rbase = m0 + rm + tm * 16 + (lane >> 4) * 4;
        #pragma unroll
        for (int i = 0; i < 4; ++i) {
            int row = rbase + i;
            if (row < M) {
                #pragma unroll
                for (int tn = 0; tn < 4; ++tn)
                    H[(size_t)row * HC + n0 + rn + tn * 16 + fr] = acc[tm][tn][i];
            }
        }
    }
}

// ---------------- per-node attention logits ----------------

__global__ __launch_bounds__(256) void esed_kernel(const float* __restrict__ H,
                                                   const float* __restrict__ a_src,
                                                   const float* __restrict__ a_dst,
                                                   float* __restrict__ es, float* __restrict__ ed) {
    int tid = threadIdx.x;
    int lane = tid & 63;
    int node = blockIdx.x * 4 + (tid >> 6);
    int head = lane >> 4;
    int cc = (lane & 15) * 4;
    float4 h4 = *(const float4*)(H + (size_t)node * HC + lane * 4);
    float4 as = *(const float4*)(a_src + head * CHAN + cc);
    float4 ad = *(const float4*)(a_dst + head * CHAN + cc);
    float ps = h4.x * as.x + h4.y * as.y + h4.z * as.z + h4.w * as.w;
    float pd = h4.x * ad.x + h4.y * ad.y + h4.z * ad.z + h4.w * ad.w;
    #pragma unroll
    for (int m = 1; m < 16; m <<= 1) {
        ps += __shfl_xor(ps, m, 64);
        pd += __shfl_xor(pd, m, 64);
    }
    if ((lane & 15) == 0) {
        es[node * NHEAD + head] = ps;
        ed[node * NHEAD + head] = pd;
    }
}

// ---------------- fused edge-softmax + aggregation: ONE WAVE per dst node ----------------
// No LDS, no __syncthreads. Phase A: online softmax stats (lane = edge).
// Phase B: edge-serial, wave covers all 256 channels (float4/lane), alpha recomputed
// from L2-hot es/csr_src (tiny vs the 1KB h[src] row).

__global__ __launch_bounds__(256) void gat_aggregate_kernel(
        const float* __restrict__ H, const float* __restrict__ es, const float* __restrict__ ed,
        const int* __restrict__ offsets, const int* __restrict__ csr_src,
        const float* __restrict__ bias, float* __restrict__ out, int do_relu) {
    int tid = threadIdx.x;
    int w = tid >> 6, lane = tid & 63;
    int n = blockIdx.x * 4 + w;
    int off = offsets[n];
    int deg = offsets[n + 1] - off;
    float4 edv = *(const float4*)(ed + (size_t)n * 4);

    // Phase A: per-lane online softmax over strided edges
    float m[4] = {-1e30f, -1e30f, -1e30f, -1e30f};
    float l[4] = {0.f, 0.f, 0.f, 0.f};
    for (int base = 0; base < deg; base += 64) {
        int j = base + lane;
        if (j < deg) {
            int s = csr_src[off + j];
            float4 esv = *(const float4*)(es + (size_t)s * 4);
            float e[4] = {esv.x + edv.x, esv.y + edv.y, esv.z + edv.z, esv.w + edv.w};
            #pragma unroll
            for (int h = 0; h < 4; ++h) {
                e[h] = (e[h] > 0.f) ? e[h] : NEG * e[h];
                float M2 = fmaxf(m[h], e[h]);
                l[h] = l[h] * __expf(m[h] - M2) + __expf(e[h] - M2);
                m[h] = M2;
            }
        }
    }
    // 64-lane butterfly combine of (m,l)
    #pragma unroll
    for (int msk = 1; msk < 64; msk <<= 1) {
        #pragma unroll
        for (int h = 0; h < 4; ++h) {
            float mo = __shfl_xor(m[h], msk, 64);
            float lo = __shfl_xor(l[h], msk, 64);
            float M2 = fmaxf(m[h], mo);
            l[h] = l[h] * __expf(m[h] - M2) + lo * __expf(mo - M2);
            m[h] = M2;
        }
    }
    int head = lane >> 4;
    float fm = m[head];
    float fr = 1.f / (l[head] + 1e-16f);
    float edh = ed[(size_t)n * 4 + head];

    // Phase B: edge-serial weighted gather; wave covers all 256 channels
    float4 acc = make_float4(0.f, 0.f, 0.f, 0.f);
    for (int j = 0; j < deg; ++j) {
        int s = csr_src[off + j];
        float e = es[(size_t)s * 4 + head] + edh;
        e = (e > 0.f) ? e : NEG * e;
        float alpha = __expf(e - fm) * fr;
        float4 h4 = *(const float4*)(H + (size_t)s * HC + lane * 4);
        acc.x += alpha * h4.x; acc.y += alpha * h4.y;
        acc.z += alpha * h4.z; acc.w += alpha * h4.w;
    }
    float4 b4 = *(const float4*)(bias + lane * 4);
    float4 o;
    o.x = acc.x + b4.x; o.y = acc.y + b4.y;
    o.z = acc.z + b4.z; o.w = acc.w + b4.w;
    if (do_relu) {
        o.x = fmaxf(o.x, 0.f); o.y = fmaxf(o.y, 0.f);
        o.z = fmaxf(o.z, 0.f); o.w = fmaxf(o.w, 0.f);
    }
    *(float4*)(out + (size_t)n * HC + lane * 4) = o;
}

// ---------------- launch ----------------

extern "C" void kernel_launch(void* const* d_in, const int* in_sizes, int n_in,
                              void* d_out, int out_size, void* d_ws, size_t ws_size,
                              hipStream_t stream) {
    const float* x  = (const float*)d_in[0];
    const int*   ei = (const int*)d_in[1];
    const float *W[5], *Asrc[5], *Adst[5], *Bs[5];
    for (int l = 0; l < 4; ++l) {
        W[l]    = (const float*)d_in[2 + l * 4];
        Asrc[l] = (const float*)d_in[3 + l * 4];
        Adst[l] = (const float*)d_in[4 + l * 4];
        Bs[l]   = (const float*)d_in[5 + l * 4];
    }
    W[4] = W[3]; Asrc[4] = Asrc[3]; Adst[4] = Adst[3]; Bs[4] = Bs[3];

    char* ws = (char*)d_ws;
    size_t off = 0;
    auto alloc = [&](size_t bytes) -> void* {
        void* p = ws + off;
        off += (bytes + 255) & ~(size_t)255;
        return p;
    };
    float* h       = (float*)alloc((size_t)N_NODES * HC * 4);
    float* xa      = (float*)alloc((size_t)N_NODES * HC * 4);
    float* xb      = (float*)alloc((size_t)N_NODES * HC * 4);
    float* xc      = (float*)alloc((size_t)N_NODES * HC * 4);
    float* es      = (float*)alloc((size_t)N_NODES * 4 * 4);
    float* ed      = (float*)alloc((size_t)N_NODES * 4 * 4);
    int*   counts  = (int*)alloc((size_t)N_NODES * 4);
    int*   offsets = (int*)alloc((size_t)(N_NODES + 1) * 4);
    int*   cursor  = (int*)alloc((size_t)N_NODES * 4);
    int*   csr_src = (int*)alloc((size_t)ETOT * 4);
    _Float16 *Wth[5], *Wtl[5];
    int Ks[4] = {128, 256, 256, 256};
    for (int l = 0; l < 4; ++l) {
        Wth[l] = (_Float16*)alloc((size_t)256 * Ks[l] * 2);
        Wtl[l] = (_Float16*)alloc((size_t)256 * Ks[l] * 2);
    }
    Wth[4] = Wth[3]; Wtl[4] = Wtl[3];

    // CSR by dst, built once per call, reused across all 5 layers
    hipMemsetAsync(counts, 0, (size_t)N_NODES * 4, stream);
    count_kernel<<<(ETOT + 255) / 256, 256, 0, stream>>>(ei, counts);
    scan_kernel<<<1, 1024, 0, stream>>>(counts, offsets, cursor);
    fill_kernel<<<(ETOT + 255) / 256, 256, 0, stream>>>(ei, cursor, csr_src);
    // weight split (once per call)
    for (int l = 0; l < 4; ++l)
        wsplit_kernel<<<(Ks[l] * 256 + 255) / 256, 256, 0, stream>>>(W[l], Wth[l], Wtl[l], Ks[l]);

    auto layer = [&](const float* in1, const float* in2, int K, int l, float* outp, int relu) {
        dim3 g((N_NODES + 127) / 128, 2);
        gemm_mfma_kernel<<<g, 256, 0, stream>>>(in1, in2, Wth[l], Wtl[l], h, N_NODES, K);
        esed_kernel<<<N_NODES / 4, 256, 0, stream>>>(h, Asrc[l], Adst[l], es, ed);
        gat_aggregate_kernel<<<N_NODES / 4, 256, 0, stream>>>(h, es, ed, offsets, csr_src,
                                                              Bs[l], outp, relu);
    };

    float* out = (float*)d_out;
    layer(x,  nullptr, 128, 0, xa, 1);  // x1 = relu(gat(x))
    layer(xa, nullptr, 256, 1, xb, 1);  // x2 = relu(gat(x1))
    layer(xb, xa,      256, 2, xc, 1);  // x3 = relu(gat(x2+x1))
    layer(xb, xc,      256, 3, xa, 1);  // x4 = relu(gat(x2+x3))
    layer(xa, xc,      256, 4, out, 0); // x5 = gat(x4+x3), no relu
}